// Round 9
// baseline (14165.784 us; speedup 1.0000x reference)
//
#include <hip/hip_runtime.h>

// IntegratedNCA R9: R6-verified 4-way split-bf16 MFMA math; tile shrunk so the
// accumulator fits the register file (R6/R8 spilled ~600MB/step with acc[8][4]=128 regs).
//  - 128 threads = 2 waves; 4x16 = 64-pixel tile; each wave owns 32 pixels -> acc[8][2] = 64 regs.
//  - Phase A: 2 threads per pixel (g=tid>>6 handles channels 8g..8g+7), streaming split_store8.
//  - __launch_bounds__(128,3): VGPR budget ~170 (live ~130), 6 blocks/CU = LDS cap (24KB panel).
// K layout (identical to R6): 10 groups x 48 cols = 480 cols = 15 K-steps.
//   gidx: 0=(h,m) 1=(m,h) 2=(h,l) 3=(m,m) 4=(l,h) 5=(h,q) 6=(m,l) 7=(l,m) 8=(q,h) 9=(h,h)
//   a-type tab 0x39244, w-type tab 0x6C61. (h,h) accumulated last.
// Panel row: 4 sections [h|m|l|q] x 48 bf16 = 384 B, 16B slots, XOR-swz slot^(row&7).
// Channels 0-7 of vkind k -> slot 2k+0, channels 8-15 -> slot 2k+1 of each section.

typedef short short8 __attribute__((ext_vector_type(8)));
typedef float floatx4 __attribute__((ext_vector_type(4)));

#define CCH   16
#define HID   128
#define BATCH 16
#define HH    128
#define WW    128
#define NIN   112
#define STEPS 10
#define NKS   15
#define ROWB  384
#define NPIX  64
#define ATAB  0x39244
#define WTAB  0x6C61

__device__ inline unsigned short f2bf(float f) {          // RN-even fp32->bf16
    unsigned u = __float_as_uint(f);
    u += 0x7fffu + ((u >> 16) & 1u);
    return (unsigned short)(u >> 16);
}
__device__ inline float bf2f(unsigned short h) { return __uint_as_float(((unsigned)h) << 16); }

// Stream-split 8 values into the 4 panel sections at slot `slot` (static, tiny live set).
__device__ __forceinline__ void split_store8(const float (&v)[8], unsigned char* rowp,
                                             int swz, int slot) {
    unsigned short a[8]; float r[8];
    #pragma unroll
    for (int e = 0; e < 8; ++e) { a[e] = f2bf(v[e]); r[e] = v[e] - bf2f(a[e]); }
    uint4 u;
    u.x = (unsigned)a[0] | ((unsigned)a[1] << 16);
    u.y = (unsigned)a[2] | ((unsigned)a[3] << 16);
    u.z = (unsigned)a[4] | ((unsigned)a[5] << 16);
    u.w = (unsigned)a[6] | ((unsigned)a[7] << 16);
    *(uint4*)(rowp + (((0 * 6 + slot) * 16) ^ swz)) = u;           // sec 0: h
    #pragma unroll
    for (int e = 0; e < 8; ++e) { a[e] = f2bf(r[e]); r[e] = r[e] - bf2f(a[e]); }
    u.x = (unsigned)a[0] | ((unsigned)a[1] << 16);
    u.y = (unsigned)a[2] | ((unsigned)a[3] << 16);
    u.z = (unsigned)a[4] | ((unsigned)a[5] << 16);
    u.w = (unsigned)a[6] | ((unsigned)a[7] << 16);
    *(uint4*)(rowp + (((1 * 6 + slot) * 16) ^ swz)) = u;           // sec 1: m
    #pragma unroll
    for (int e = 0; e < 8; ++e) { a[e] = f2bf(r[e]); r[e] = r[e] - bf2f(a[e]); }
    u.x = (unsigned)a[0] | ((unsigned)a[1] << 16);
    u.y = (unsigned)a[2] | ((unsigned)a[3] << 16);
    u.z = (unsigned)a[4] | ((unsigned)a[5] << 16);
    u.w = (unsigned)a[6] | ((unsigned)a[7] << 16);
    *(uint4*)(rowp + (((2 * 6 + slot) * 16) ^ swz)) = u;           // sec 2: l
    #pragma unroll
    for (int e = 0; e < 8; ++e) a[e] = f2bf(r[e]);
    u.x = (unsigned)a[0] | ((unsigned)a[1] << 16);
    u.y = (unsigned)a[2] | ((unsigned)a[3] << 16);
    u.z = (unsigned)a[4] | ((unsigned)a[5] << 16);
    u.w = (unsigned)a[6] | ((unsigned)a[7] << 16);
    *(uint4*)(rowp + (((3 * 6 + slot) * 16) ^ swz)) = u;           // sec 3: q
}

// ---------------- prep: folded bias, W2 transpose, 4-way W1 fragment pack ----------------
__global__ __launch_bounds__(256) void nca_prep(
    const float* __restrict__ W1, const float* __restrict__ b1,
    const float* __restrict__ w,  const float* __restrict__ W2,
    float* __restrict__ biasw, float* __restrict__ W2t, unsigned short* __restrict__ W1p)
{
    const int t = threadIdx.x;
    for (int i = t; i < BATCH * HID; i += 256) {
        int b = i / HID, h = i % HID;
        float acc = b1[h];
        const float* wrow  = w  + b * 64;
        const float* W1row = W1 + h * NIN + 48;
        #pragma unroll
        for (int j = 0; j < 64; ++j) acc = fmaf(W1row[j], wrow[j], acc);
        biasw[i] = acc;
    }
    for (int i = t; i < HID * CCH; i += 256) {
        int h = i / CCH, c = i % CCH;
        W2t[h * CCH + c] = W2[c * HID + h];
    }
    for (int i = t; i < NKS * 8 * 64 * 8; i += 256) {
        int j = i & 7, lane = (i >> 3) & 63, Mt = (i >> 9) & 7, ks = i >> 12;
        int col = ks * 32 + ((lane >> 4) << 3) + j;         // 0..479
        int grp = col / 48, within = col - grp * 48;
        int u = (WTAB >> (grp << 1)) & 3;
        int h = Mt * 16 + (lane & 15);
        float base = W1[h * NIN + within];
        unsigned short wh = f2bf(base), v;
        if (u == 0) v = wh;
        else {
            float r1 = base - bf2f(wh);
            unsigned short wm = f2bf(r1);
            if (u == 1) v = wm;
            else {
                float r2 = r1 - bf2f(wm);
                unsigned short wl = f2bf(r2);
                v = (u == 2) ? wl : f2bf(r2 - bf2f(wl));
            }
        }
        W1p[i] = v;
    }
}

// ---------------- per-step kernel: 128 threads, 4x16 pixel tile (64 pixels) ----------------
__global__ __launch_bounds__(128, 3) void nca_step(
    const float* __restrict__ xin, float* __restrict__ xout,
    const unsigned short* __restrict__ W1p, const float* __restrict__ W2t,
    const float* __restrict__ b2, const float* __restrict__ biasw)
{
    __shared__ __align__(16) unsigned char panel[NPIX * ROWB];   // 24 KB

    const int b   = blockIdx.z;
    const int ty0 = blockIdx.y * 4, tx0 = blockIdx.x * 16;
    const int tid  = threadIdx.x;
    const int pix  = tid & 63;               // pixel in tile
    const int g    = tid >> 6;               // channel half: 0 -> c 0..7, 1 -> c 8..15
    const int lane = tid & 63, wv = tid >> 6;
    const int q = lane >> 4, pcol = lane & 15;
    const float* xb = xin + b * (CCH * HH * WW);

    // ---- taps from global (clamped addr + zero mask == zero-pad), sobel, stream splits ----
    const int py = pix >> 4, px = pix & 15;
    const int gy = ty0 + py, gx = tx0 + px;
    int   o0,o1,o2,o3,o4,o5,o6,o7,o8;
    float m0,m1,m2,m5,m6,m7,m8, m3v,m4v;
    {
        int cym = max(gy - 1, 0), cyp = min(gy + 1, HH - 1);
        int cxm = max(gx - 1, 0), cxp = min(gx + 1, WW - 1);
        float vym = (gy - 1 >= 0) ? 1.f : 0.f, vyp = (gy + 1 < HH) ? 1.f : 0.f;
        float vxm = (gx - 1 >= 0) ? 1.f : 0.f, vxp = (gx + 1 < WW) ? 1.f : 0.f;
        o0 = cym * WW + cxm; m0 = vym * vxm;
        o1 = cym * WW + gx;  m1 = vym;
        o2 = cym * WW + cxp; m2 = vym * vxp;
        o3 = gy  * WW + cxm; m3v = vxm;
        o4 = gy  * WW + gx;  m4v = 1.f;
        o5 = gy  * WW + cxp; m5 = vxp;
        o6 = cyp * WW + cxm; m6 = vyp * vxm;
        o7 = cyp * WW + gx;  m7 = vyp;
        o8 = cyp * WW + cxp; m8 = vyp * vxp;
    }
    unsigned char* rowp = panel + pix * ROWB;
    const int swz = (pix & 7) << 4;
    bool pre_life = false;

    {
        float vx[8], vgx[8], vgy[8];
        #pragma unroll
        for (int cc = 0; cc < 8; ++cc) {
            const float* xc = xb + (g * 8 + cc) * (HH * WW);
            float t0 = xc[o0]*m0, t1 = xc[o1]*m1, t2 = xc[o2]*m2;
            float t3 = xc[o3]*m3v, t4 = xc[o4]*m4v, t5 = xc[o5]*m5;
            float t6 = xc[o6]*m6, t7 = xc[o7]*m7, t8 = xc[o8]*m8;
            vx[cc]  = t4;
            vgx[cc] = (t2 - t0) + 2.f * (t5 - t3) + (t8 - t6);
            vgy[cc] = (t6 - t0) + 2.f * (t7 - t1) + (t8 - t2);
            if (g == 0 && cc == 3) {
                float mm = fmaxf(fmaxf(fmaxf(t0, t1), fmaxf(t2, t3)),
                                 fmaxf(fmaxf(t4, t5), fmaxf(t6, fmaxf(t7, t8))));
                pre_life = (mm > 0.1f);
            }
        }
        split_store8(vx,  rowp, swz, 0 + g);   // vkind 0 -> slot 2*0+g
        split_store8(vgx, rowp, swz, 2 + g);   // vkind 1 -> slot 2*1+g
        split_store8(vgy, rowp, swz, 4 + g);   // vkind 2 -> slot 2*2+g
    }
    __syncthreads();

    // ---- GEMM1 (MFMA, 15 K-steps, zero-init; (h,h) group = cols 432..479 = last) ----
    // Wave wv owns pixels 32*wv .. 32*wv+31 (2 N-tiles). acc[8][2] = 64 VGPRs.
    floatx4 acc[8][2];
    #pragma unroll
    for (int Mt = 0; Mt < 8; ++Mt)
        #pragma unroll
        for (int n2 = 0; n2 < 2; ++n2)
            acc[Mt][n2] = (floatx4){0.f, 0.f, 0.f, 0.f};

    #pragma unroll
    for (int ks = 0; ks < NKS; ++ks) {
        int col0 = ks * 32 + (q << 3);
        int grp = (col0 * 171) >> 13;                 // col0/48, valid to 479
        int within = col0 - grp * 48;
        int vsel = (ATAB >> (grp << 1)) & 3;
        int kb = vsel * 96 + (within << 1);
        short8 bfr[2];
        #pragma unroll
        for (int n2 = 0; n2 < 2; ++n2) {
            int prow = wv * 32 + n2 * 16 + pcol;
            bfr[n2] = *(const short8*)(panel + prow * ROWB + (kb ^ ((prow & 7) << 4)));
        }
        #pragma unroll
        for (int Mh = 0; Mh < 2; ++Mh) {              // A-frags in 2 groups of 4
            short8 af[4];
            #pragma unroll
            for (int m = 0; m < 4; ++m)
                af[m] = *(const short8*)(W1p + ((ks * 8 + Mh * 4 + m) * 64 + lane) * 8);
            #pragma unroll
            for (int n2 = 0; n2 < 2; ++n2)
                #pragma unroll
                for (int m = 0; m < 4; ++m)
                    acc[Mh * 4 + m][n2] =
                        __builtin_amdgcn_mfma_f32_16x16x32_bf16(af[m], bfr[n2], acc[Mh * 4 + m][n2], 0, 0, 0);
        }
    }

    __syncthreads();                       // all panel reads done -> reuse as ds/alive buffer
    float* dsl = (float*)panel;            // [64][17] f32 (+ slot 16 = alive)

    // ---- GEMM2 (fp32 VALU), bias here: lane owns h = Mt*16 + q*4 + r for its 2 n-tiles ----
    {
        float dsp[2][16];
        #pragma unroll
        for (int n2 = 0; n2 < 2; ++n2)
            #pragma unroll
            for (int c = 0; c < 16; ++c) dsp[n2][c] = 0.f;
        #pragma unroll
        for (int Mt = 0; Mt < 8; ++Mt) {
            floatx4 bv = *(const floatx4*)(biasw + b * HID + Mt * 16 + q * 4);
            #pragma unroll
            for (int r = 0; r < 4; ++r) {
                const floatx4* w2p = (const floatx4*)(W2t + (Mt * 16 + q * 4 + r) * 16);
                floatx4 wa = w2p[0], wb = w2p[1], wc = w2p[2], wd = w2p[3];
                #pragma unroll
                for (int n2 = 0; n2 < 2; ++n2) {
                    float hv = fmaxf(acc[Mt][n2][r] + bv[r], 0.f);
                    dsp[n2][0]  = fmaf(hv, wa[0], dsp[n2][0]);
                    dsp[n2][1]  = fmaf(hv, wa[1], dsp[n2][1]);
                    dsp[n2][2]  = fmaf(hv, wa[2], dsp[n2][2]);
                    dsp[n2][3]  = fmaf(hv, wa[3], dsp[n2][3]);
                    dsp[n2][4]  = fmaf(hv, wb[0], dsp[n2][4]);
                    dsp[n2][5]  = fmaf(hv, wb[1], dsp[n2][5]);
                    dsp[n2][6]  = fmaf(hv, wb[2], dsp[n2][6]);
                    dsp[n2][7]  = fmaf(hv, wb[3], dsp[n2][7]);
                    dsp[n2][8]  = fmaf(hv, wc[0], dsp[n2][8]);
                    dsp[n2][9]  = fmaf(hv, wc[1], dsp[n2][9]);
                    dsp[n2][10] = fmaf(hv, wc[2], dsp[n2][10]);
                    dsp[n2][11] = fmaf(hv, wc[3], dsp[n2][11]);
                    dsp[n2][12] = fmaf(hv, wd[0], dsp[n2][12]);
                    dsp[n2][13] = fmaf(hv, wd[1], dsp[n2][13]);
                    dsp[n2][14] = fmaf(hv, wd[2], dsp[n2][14]);
                    dsp[n2][15] = fmaf(hv, wd[3], dsp[n2][15]);
                }
            }
        }
        #pragma unroll
        for (int n2 = 0; n2 < 2; ++n2) {
            #pragma unroll
            for (int c = 0; c < 16; ++c) {
                float v = dsp[n2][c];
                v += __shfl_xor(v, 16);
                v += __shfl_xor(v, 32);
                if ((c >> 2) == q)
                    dsl[(wv * 32 + n2 * 16 + pcol) * 17 + c] = v;
            }
        }
    }
    __syncthreads();

    // ---- life gate: owner thread (g==0) computes alive, shares via dsl slot 16 ----
    const int gidx = gy * WW + gx;
    if (g == 0) {
        float ds3 = dsl[pix * 17 + 3] + b2[3];
        float x3  = xb[3 * HH * WW + gidx];
        float alive = ((x3 + ds3) > 0.1f && pre_life) ? 1.f : 0.f;
        dsl[pix * 17 + 16] = alive;
    }
    __syncthreads();

    // ---- residual + gate + store: each thread writes its 8 channels ----
    float alive = dsl[pix * 17 + 16];
    float* ob = xout + b * (CCH * HH * WW);
    #pragma unroll
    for (int cc = 0; cc < 8; ++cc) {
        int c = g * 8 + cc;
        float nv = xb[c * HH * WW + gidx] + dsl[pix * 17 + c] + b2[c];
        ob[c * HH * WW + gidx] = nv * alive;
    }
}

extern "C" void kernel_launch(void* const* d_in, const int* in_sizes, int n_in,
                              void* d_out, int out_size, void* d_ws, size_t ws_size,
                              hipStream_t stream) {
    const float* x   = (const float*)d_in[0];
    const float* w   = (const float*)d_in[1];
    const float* W1  = (const float*)d_in[2];
    const float* b1  = (const float*)d_in[3];
    const float* W2  = (const float*)d_in[4];
    const float* b2  = (const float*)d_in[5];
    float* out = (float*)d_out;

    float* ws0   = (float*)d_ws;                          // 16.8 MB ping-pong
    float* biasw = ws0 + BATCH * CCH * HH * WW;           // 2048 f32
    float* W2t   = biasw + BATCH * HID;                   // 2048 f32
    unsigned short* W1p = (unsigned short*)(W2t + HID * CCH); // 61440 u16

    nca_prep<<<1, 256, 0, stream>>>(W1, b1, w, W2, biasw, W2t, W1p);

    dim3 grid(WW / 16, HH / 4, BATCH);
    for (int s = 0; s < STEPS; ++s) {
        float* dst = (((STEPS - 1 - s) & 1) == 0) ? out : ws0;
        const float* src = (s == 0) ? x
                         : ((((STEPS - s) & 1) == 0) ? (const float*)out : (const float*)ws0);
        nca_step<<<grid, 128, 0, stream>>>(src, dst, W1p, W2t, b2, biasw);
    }
}

// Round 10
// 1208.339 us; speedup vs baseline: 11.7234x; 11.7234x over previous
//
#include <hip/hip_runtime.h>

// IntegratedNCA R10: R9 kernel with exactly two codegen fixes (math untouched):
//  1) __launch_bounds__(128,1): measured hipcc cap law for 2-wave blocks is 512/(2*arg);
//     R9's (128,3) capped VGPR at 84 < acc(64)+operands -> forced acc spill (4.4GB/step).
//  2) #pragma unroll 1 on the K-loop: R6/R8's fully-unrolled 240-MFMA region let the
//     scheduler hoist loads and blow past 256 regs (630MB spill at VGPR=256). Rolled
//     K-loop = bounded window, acc pinned in (acc)VGPRs - the m97-proven pattern.
// K layout (R6-verified): 10 groups x 48 cols = 480 cols = 15 K-steps of 32.
//   gidx: 0=(h,m) 1=(m,h) 2=(h,l) 3=(m,m) 4=(l,h) 5=(h,q) 6=(m,l) 7=(l,m) 8=(q,h) 9=(h,h)
//   a-type tab 0x39244, w-type tab 0x6C61. (h,h) accumulated last.
// Panel row: 4 sections [h|m|l|q] x 48 bf16 = 384 B, 16B slots, XOR-swz slot^(row&7).
// Channels 0-7 of vkind k -> slot 2k+0, channels 8-15 -> slot 2k+1 of each section.

typedef short short8 __attribute__((ext_vector_type(8)));
typedef float floatx4 __attribute__((ext_vector_type(4)));

#define CCH   16
#define HID   128
#define BATCH 16
#define HH    128
#define WW    128
#define NIN   112
#define STEPS 10
#define NKS   15
#define ROWB  384
#define NPIX  64
#define ATAB  0x39244
#define WTAB  0x6C61

__device__ inline unsigned short f2bf(float f) {          // RN-even fp32->bf16
    unsigned u = __float_as_uint(f);
    u += 0x7fffu + ((u >> 16) & 1u);
    return (unsigned short)(u >> 16);
}
__device__ inline float bf2f(unsigned short h) { return __uint_as_float(((unsigned)h) << 16); }

// Stream-split 8 values into the 4 panel sections at slot `slot` (static, tiny live set).
__device__ __forceinline__ void split_store8(const float (&v)[8], unsigned char* rowp,
                                             int swz, int slot) {
    unsigned short a[8]; float r[8];
    #pragma unroll
    for (int e = 0; e < 8; ++e) { a[e] = f2bf(v[e]); r[e] = v[e] - bf2f(a[e]); }
    uint4 u;
    u.x = (unsigned)a[0] | ((unsigned)a[1] << 16);
    u.y = (unsigned)a[2] | ((unsigned)a[3] << 16);
    u.z = (unsigned)a[4] | ((unsigned)a[5] << 16);
    u.w = (unsigned)a[6] | ((unsigned)a[7] << 16);
    *(uint4*)(rowp + (((0 * 6 + slot) * 16) ^ swz)) = u;           // sec 0: h
    #pragma unroll
    for (int e = 0; e < 8; ++e) { a[e] = f2bf(r[e]); r[e] = r[e] - bf2f(a[e]); }
    u.x = (unsigned)a[0] | ((unsigned)a[1] << 16);
    u.y = (unsigned)a[2] | ((unsigned)a[3] << 16);
    u.z = (unsigned)a[4] | ((unsigned)a[5] << 16);
    u.w = (unsigned)a[6] | ((unsigned)a[7] << 16);
    *(uint4*)(rowp + (((1 * 6 + slot) * 16) ^ swz)) = u;           // sec 1: m
    #pragma unroll
    for (int e = 0; e < 8; ++e) { a[e] = f2bf(r[e]); r[e] = r[e] - bf2f(a[e]); }
    u.x = (unsigned)a[0] | ((unsigned)a[1] << 16);
    u.y = (unsigned)a[2] | ((unsigned)a[3] << 16);
    u.z = (unsigned)a[4] | ((unsigned)a[5] << 16);
    u.w = (unsigned)a[6] | ((unsigned)a[7] << 16);
    *(uint4*)(rowp + (((2 * 6 + slot) * 16) ^ swz)) = u;           // sec 2: l
    #pragma unroll
    for (int e = 0; e < 8; ++e) a[e] = f2bf(r[e]);
    u.x = (unsigned)a[0] | ((unsigned)a[1] << 16);
    u.y = (unsigned)a[2] | ((unsigned)a[3] << 16);
    u.z = (unsigned)a[4] | ((unsigned)a[5] << 16);
    u.w = (unsigned)a[6] | ((unsigned)a[7] << 16);
    *(uint4*)(rowp + (((3 * 6 + slot) * 16) ^ swz)) = u;           // sec 3: q
}

// ---------------- prep: folded bias, W2 transpose, 4-way W1 fragment pack ----------------
__global__ __launch_bounds__(256) void nca_prep(
    const float* __restrict__ W1, const float* __restrict__ b1,
    const float* __restrict__ w,  const float* __restrict__ W2,
    float* __restrict__ biasw, float* __restrict__ W2t, unsigned short* __restrict__ W1p)
{
    const int t = threadIdx.x;
    for (int i = t; i < BATCH * HID; i += 256) {
        int b = i / HID, h = i % HID;
        float acc = b1[h];
        const float* wrow  = w  + b * 64;
        const float* W1row = W1 + h * NIN + 48;
        #pragma unroll
        for (int j = 0; j < 64; ++j) acc = fmaf(W1row[j], wrow[j], acc);
        biasw[i] = acc;
    }
    for (int i = t; i < HID * CCH; i += 256) {
        int h = i / CCH, c = i % CCH;
        W2t[h * CCH + c] = W2[c * HID + h];
    }
    for (int i = t; i < NKS * 8 * 64 * 8; i += 256) {
        int j = i & 7, lane = (i >> 3) & 63, Mt = (i >> 9) & 7, ks = i >> 12;
        int col = ks * 32 + ((lane >> 4) << 3) + j;         // 0..479
        int grp = col / 48, within = col - grp * 48;
        int u = (WTAB >> (grp << 1)) & 3;
        int h = Mt * 16 + (lane & 15);
        float base = W1[h * NIN + within];
        unsigned short wh = f2bf(base), v;
        if (u == 0) v = wh;
        else {
            float r1 = base - bf2f(wh);
            unsigned short wm = f2bf(r1);
            if (u == 1) v = wm;
            else {
                float r2 = r1 - bf2f(wm);
                unsigned short wl = f2bf(r2);
                v = (u == 2) ? wl : f2bf(r2 - bf2f(wl));
            }
        }
        W1p[i] = v;
    }
}

// ---------------- per-step kernel: 128 threads, 4x16 pixel tile (64 pixels) ----------------
__global__ __launch_bounds__(128, 1) void nca_step(
    const float* __restrict__ xin, float* __restrict__ xout,
    const unsigned short* __restrict__ W1p, const float* __restrict__ W2t,
    const float* __restrict__ b2, const float* __restrict__ biasw)
{
    __shared__ __align__(16) unsigned char panel[NPIX * ROWB];   // 24 KB

    const int b   = blockIdx.z;
    const int ty0 = blockIdx.y * 4, tx0 = blockIdx.x * 16;
    const int tid  = threadIdx.x;
    const int pix  = tid & 63;               // pixel in tile
    const int g    = tid >> 6;               // channel half: 0 -> c 0..7, 1 -> c 8..15
    const int lane = tid & 63, wv = tid >> 6;
    const int q = lane >> 4, pcol = lane & 15;
    const float* xb = xin + b * (CCH * HH * WW);

    // ---- taps from global (clamped addr + zero mask == zero-pad), sobel, stream splits ----
    const int py = pix >> 4, px = pix & 15;
    const int gy = ty0 + py, gx = tx0 + px;
    int   o0,o1,o2,o3,o4,o5,o6,o7,o8;
    float m0,m1,m2,m5,m6,m7,m8, m3v,m4v;
    {
        int cym = max(gy - 1, 0), cyp = min(gy + 1, HH - 1);
        int cxm = max(gx - 1, 0), cxp = min(gx + 1, WW - 1);
        float vym = (gy - 1 >= 0) ? 1.f : 0.f, vyp = (gy + 1 < HH) ? 1.f : 0.f;
        float vxm = (gx - 1 >= 0) ? 1.f : 0.f, vxp = (gx + 1 < WW) ? 1.f : 0.f;
        o0 = cym * WW + cxm; m0 = vym * vxm;
        o1 = cym * WW + gx;  m1 = vym;
        o2 = cym * WW + cxp; m2 = vym * vxp;
        o3 = gy  * WW + cxm; m3v = vxm;
        o4 = gy  * WW + gx;  m4v = 1.f;
        o5 = gy  * WW + cxp; m5 = vxp;
        o6 = cyp * WW + cxm; m6 = vyp * vxm;
        o7 = cyp * WW + gx;  m7 = vyp;
        o8 = cyp * WW + cxp; m8 = vyp * vxp;
    }
    unsigned char* rowp = panel + pix * ROWB;
    const int swz = (pix & 7) << 4;
    bool pre_life = false;

    {
        float vx[8], vgx[8], vgy[8];
        #pragma unroll
        for (int cc = 0; cc < 8; ++cc) {
            const float* xc = xb + (g * 8 + cc) * (HH * WW);
            float t0 = xc[o0]*m0, t1 = xc[o1]*m1, t2 = xc[o2]*m2;
            float t3 = xc[o3]*m3v, t4 = xc[o4]*m4v, t5 = xc[o5]*m5;
            float t6 = xc[o6]*m6, t7 = xc[o7]*m7, t8 = xc[o8]*m8;
            vx[cc]  = t4;
            vgx[cc] = (t2 - t0) + 2.f * (t5 - t3) + (t8 - t6);
            vgy[cc] = (t6 - t0) + 2.f * (t7 - t1) + (t8 - t2);
            if (g == 0 && cc == 3) {
                float mm = fmaxf(fmaxf(fmaxf(t0, t1), fmaxf(t2, t3)),
                                 fmaxf(fmaxf(t4, t5), fmaxf(t6, fmaxf(t7, t8))));
                pre_life = (mm > 0.1f);
            }
        }
        split_store8(vx,  rowp, swz, 0 + g);   // vkind 0 -> slot 2*0+g
        split_store8(vgx, rowp, swz, 2 + g);   // vkind 1 -> slot 2*1+g
        split_store8(vgy, rowp, swz, 4 + g);   // vkind 2 -> slot 2*2+g
    }
    __syncthreads();

    // ---- GEMM1 (MFMA, 15 K-steps, ROLLED loop; (h,h) group = cols 432..479 = last) ----
    // Wave wv owns pixels 32*wv .. 32*wv+31 (2 N-tiles). acc[8][2] = 64 regs, stays resident.
    floatx4 acc[8][2];
    #pragma unroll
    for (int Mt = 0; Mt < 8; ++Mt)
        #pragma unroll
        for (int n2 = 0; n2 < 2; ++n2)
            acc[Mt][n2] = (floatx4){0.f, 0.f, 0.f, 0.f};

    #pragma unroll 1
    for (int ks = 0; ks < NKS; ++ks) {
        int col0 = ks * 32 + (q << 3);
        int grp = (col0 * 171) >> 13;                 // col0/48, valid to 479
        int within = col0 - grp * 48;
        int vsel = (ATAB >> (grp << 1)) & 3;
        int kb = vsel * 96 + (within << 1);
        short8 bfr[2];
        #pragma unroll
        for (int n2 = 0; n2 < 2; ++n2) {
            int prow = wv * 32 + n2 * 16 + pcol;
            bfr[n2] = *(const short8*)(panel + prow * ROWB + (kb ^ ((prow & 7) << 4)));
        }
        #pragma unroll
        for (int Mh = 0; Mh < 2; ++Mh) {              // A-frags in 2 groups of 4
            short8 af[4];
            #pragma unroll
            for (int m = 0; m < 4; ++m)
                af[m] = *(const short8*)(W1p + ((ks * 8 + Mh * 4 + m) * 64 + lane) * 8);
            #pragma unroll
            for (int n2 = 0; n2 < 2; ++n2)
                #pragma unroll
                for (int m = 0; m < 4; ++m)
                    acc[Mh * 4 + m][n2] =
                        __builtin_amdgcn_mfma_f32_16x16x32_bf16(af[m], bfr[n2], acc[Mh * 4 + m][n2], 0, 0, 0);
        }
    }

    __syncthreads();                       // all panel reads done -> reuse as ds/alive buffer
    float* dsl = (float*)panel;            // [64][17] f32 (+ slot 16 = alive)

    // ---- GEMM2 (fp32 VALU), bias here: lane owns h = Mt*16 + q*4 + r for its 2 n-tiles ----
    {
        float dsp[2][16];
        #pragma unroll
        for (int n2 = 0; n2 < 2; ++n2)
            #pragma unroll
            for (int c = 0; c < 16; ++c) dsp[n2][c] = 0.f;
        #pragma unroll 1
        for (int Mt = 0; Mt < 8; ++Mt) {
            floatx4 bv = *(const floatx4*)(biasw + b * HID + Mt * 16 + q * 4);
            #pragma unroll
            for (int r = 0; r < 4; ++r) {
                const floatx4* w2p = (const floatx4*)(W2t + (Mt * 16 + q * 4 + r) * 16);
                floatx4 wa = w2p[0], wb = w2p[1], wc = w2p[2], wd = w2p[3];
                #pragma unroll
                for (int n2 = 0; n2 < 2; ++n2) {
                    float hv = fmaxf(acc[Mt][n2][r] + bv[r], 0.f);
                    dsp[n2][0]  = fmaf(hv, wa[0], dsp[n2][0]);
                    dsp[n2][1]  = fmaf(hv, wa[1], dsp[n2][1]);
                    dsp[n2][2]  = fmaf(hv, wa[2], dsp[n2][2]);
                    dsp[n2][3]  = fmaf(hv, wa[3], dsp[n2][3]);
                    dsp[n2][4]  = fmaf(hv, wb[0], dsp[n2][4]);
                    dsp[n2][5]  = fmaf(hv, wb[1], dsp[n2][5]);
                    dsp[n2][6]  = fmaf(hv, wb[2], dsp[n2][6]);
                    dsp[n2][7]  = fmaf(hv, wb[3], dsp[n2][7]);
                    dsp[n2][8]  = fmaf(hv, wc[0], dsp[n2][8]);
                    dsp[n2][9]  = fmaf(hv, wc[1], dsp[n2][9]);
                    dsp[n2][10] = fmaf(hv, wc[2], dsp[n2][10]);
                    dsp[n2][11] = fmaf(hv, wc[3], dsp[n2][11]);
                    dsp[n2][12] = fmaf(hv, wd[0], dsp[n2][12]);
                    dsp[n2][13] = fmaf(hv, wd[1], dsp[n2][13]);
                    dsp[n2][14] = fmaf(hv, wd[2], dsp[n2][14]);
                    dsp[n2][15] = fmaf(hv, wd[3], dsp[n2][15]);
                }
            }
        }
        #pragma unroll
        for (int n2 = 0; n2 < 2; ++n2) {
            #pragma unroll
            for (int c = 0; c < 16; ++c) {
                float v = dsp[n2][c];
                v += __shfl_xor(v, 16);
                v += __shfl_xor(v, 32);
                if ((c >> 2) == q)
                    dsl[(wv * 32 + n2 * 16 + pcol) * 17 + c] = v;
            }
        }
    }
    __syncthreads();

    // ---- life gate: owner thread (g==0) computes alive, shares via dsl slot 16 ----
    const int gidx = gy * WW + gx;
    if (g == 0) {
        float ds3 = dsl[pix * 17 + 3] + b2[3];
        float x3  = xb[3 * HH * WW + gidx];
        float alive = ((x3 + ds3) > 0.1f && pre_life) ? 1.f : 0.f;
        dsl[pix * 17 + 16] = alive;
    }
    __syncthreads();

    // ---- residual + gate + store: each thread writes its 8 channels ----
    float alive = dsl[pix * 17 + 16];
    float* ob = xout + b * (CCH * HH * WW);
    #pragma unroll
    for (int cc = 0; cc < 8; ++cc) {
        int c = g * 8 + cc;
        float nv = xb[c * HH * WW + gidx] + dsl[pix * 17 + c] + b2[c];
        ob[c * HH * WW + gidx] = nv * alive;
    }
}

extern "C" void kernel_launch(void* const* d_in, const int* in_sizes, int n_in,
                              void* d_out, int out_size, void* d_ws, size_t ws_size,
                              hipStream_t stream) {
    const float* x   = (const float*)d_in[0];
    const float* w   = (const float*)d_in[1];
    const float* W1  = (const float*)d_in[2];
    const float* b1  = (const float*)d_in[3];
    const float* W2  = (const float*)d_in[4];
    const float* b2  = (const float*)d_in[5];
    float* out = (float*)d_out;

    float* ws0   = (float*)d_ws;                          // 16.8 MB ping-pong
    float* biasw = ws0 + BATCH * CCH * HH * WW;           // 2048 f32
    float* W2t   = biasw + BATCH * HID;                   // 2048 f32
    unsigned short* W1p = (unsigned short*)(W2t + HID * CCH); // 61440 u16

    nca_prep<<<1, 256, 0, stream>>>(W1, b1, w, W2, biasw, W2t, W1p);

    dim3 grid(WW / 16, HH / 4, BATCH);
    for (int s = 0; s < STEPS; ++s) {
        float* dst = (((STEPS - 1 - s) & 1) == 0) ? out : ws0;
        const float* src = (s == 0) ? x
                         : ((((STEPS - s) & 1) == 0) ? (const float*)out : (const float*)ws0);
        nca_step<<<grid, 128, 0, stream>>>(src, dst, W1p, W2t, b2, biasw);
    }
}